// Round 12
// baseline (611.134 us; speedup 1.0000x reference)
//
#include <hip/hip_runtime.h>
#include <math.h>

// Factorized GCN: A_hat = D^-1/2 (A+I) D^-1/2. All aggregations are
// prescale(rows by dinv) -> pure gather-sum over CSR cols -> postscale by dinv.
// CSR rows are RANK-PERMUTED by class c=i&7: rank(i) = base(c) + (i>>3), so
// each class's col region is contiguous and class-s fill blocks (-> XCD s via
// blockIdx%8) own their col lines exclusively (write-amp 2x -> 1x).
// hA stores PRESCALED h1; xp rows are 16 floats (one aligned 64B line).
// aggH is the measured fabric floor: FETCH = 8 XCD x 51 MB compulsory, ~3.9 TB/s.
// Pooling is edge-parallel on the raw edge list (no CSR, no divergence).

#define CHUNK 2048

__device__ __forceinline__ int rankof(int i, int nq, int nr) {
  int c = i & 7;
  return c * nq + min(c, nr) + (i >> 3);
}

// ---------------- setup kernels ----------------

// single-pass int histogram in RANK space: cnt_rank[rank(dst)]++
__global__ void deg_kernel(const int* __restrict__ dst, int* cnt_rank,
                           int E, int nq, int nr) {
  int e = blockIdx.x * blockDim.x + threadIdx.x;
  if (e < E) atomicAdd(&cnt_rank[rankof(dst[e], nq, nr)], 1);
}

// dinv[i] = 1/sqrt(cnt_rank[rank(i)]+1); per-block RANK-ORDER sums -> bsum;
// xp = dinv_i * x_i padded to 16 floats (one 64B line per row)
__global__ void dinv_bsum_pad_kernel(const int* __restrict__ cnt_rank,
                                     float* __restrict__ dinv, int* bsum,
                                     const float* __restrict__ x,
                                     float* __restrict__ xp, int N, int nq, int nr) {
  __shared__ int s[256];
  int t = threadIdx.x;
  int gid = blockIdx.x * 256 + t;
  // bsum basis: coalesced read of the rank-array itself (scan is in rank space)
  s[t] = (gid < N) ? cnt_rank[gid] : 0;
  if (gid < N) {
    int c = cnt_rank[rankof(gid, nq, nr)];     // this node's in-degree
    float di = 1.0f / sqrtf((float)c + 1.0f);
    dinv[gid] = di;
    const float* xr = x + (size_t)gid * 9;
    float* xo = xp + (size_t)gid * 16;
    *(float4*)(xo + 0)  = make_float4(xr[0] * di, xr[1] * di, xr[2] * di, xr[3] * di);
    *(float4*)(xo + 4)  = make_float4(xr[4] * di, xr[5] * di, xr[6] * di, xr[7] * di);
    *(float4*)(xo + 8)  = make_float4(xr[8] * di, 0.0f, 0.0f, 0.0f);
    *(float4*)(xo + 12) = make_float4(0.0f, 0.0f, 0.0f, 0.0f);
  }
  __syncthreads();
  for (int off = 128; off > 0; off >>= 1) {
    if (t < off) s[t] += s[t + off];
    __syncthreads();
  }
  if (t == 0) bsum[blockIdx.x] = s[0];
}

// rowptr over RANK space: each block computes its own bsum-prefix. Block 0 also
// computes the collapsed head (v = W3@lin_w, c0 = b3.lin_w + lin_b).
// indeg/cursor alias (both rank-indexed): read-then-write safe.
__global__ void rowptr_vc0_kernel(const int* __restrict__ indeg, const int* __restrict__ bsum,
                                  int* row_ptr, int* cursor, int N, int E,
                                  const float* __restrict__ W3, const float* __restrict__ b3,
                                  const float* __restrict__ lin_w, const float* __restrict__ lin_b,
                                  float* v, float* c0) {
  __shared__ int ps[256];
  __shared__ int s[256];
  int t = threadIdx.x;
  int pref = 0;
  for (int q = t; q < blockIdx.x; q += 256) pref += bsum[q];
  ps[t] = pref;
  __syncthreads();
  for (int off = 128; off > 0; off >>= 1) {
    if (t < off) ps[t] += ps[t + off];
    __syncthreads();
  }
  int base = ps[0];
  int r = blockIdx.x * 256 + t;
  int val = (r < N) ? indeg[r] : 0;
  s[t] = val;
  __syncthreads();
  for (int off = 1; off < 256; off <<= 1) {
    int x = (t >= off) ? s[t - off] : 0;
    __syncthreads();
    s[t] += x;
    __syncthreads();
  }
  int excl = s[t] - val + base;
  if (r < N) { row_ptr[r] = excl; cursor[r] = excl; }
  if (blockIdx.x == 0) {
    if (t == 0) row_ptr[N] = E;
    if (t < 128) {
      float sv = 0.0f;
      for (int c = 0; c < 128; ++c) sv = fmaf(W3[t * 128 + c], lin_w[c], sv);
      v[t] = sv;
    } else if (t == 128) {
      float sv = 0.0f;
      for (int c = 0; c < 128; ++c) sv = fmaf(b3[c], lin_w[c], sv);
      c0[0] = sv + lin_b[0];
    }
  }
}

// partitioned CSR fill: dst&7-matched blocks write only their class's
// contiguous col region -> each 64B col line owned by exactly one XCD
__global__ __launch_bounds__(256) void fill_part_kernel(const int* __restrict__ src,
                                                        const int* __restrict__ dst,
                                                        int* cursor, int* __restrict__ col,
                                                        int E, int nq, int nr) {
  int sub = blockIdx.x & 7;
  int base = (blockIdx.x >> 3) * CHUNK;
#pragma unroll
  for (int j = 0; j < CHUNK / 256; ++j) {
    int e = base + j * 256 + threadIdx.x;
    if (e < E) {
      int d = dst[e];
      if ((d & 7) == sub) {
        int p = atomicAdd(&cursor[rankof(d, nq, nr)], 1);
        col[p] = src[e];
      }
    }
  }
}

// ---------------- layer 1 fused: xa = dinv_i * sum(xp), hA = dinv_i * relu(xa@W1+b1) ----------------
// Per-thread gather (256 independent chains/block), x2 edge unroll, 6 aligned
// 16B gathers in flight; each xp row is exactly one 64B line.

__global__ __launch_bounds__(256) void agg9_gemm1_kernel(const float* __restrict__ xp,
    const float* __restrict__ dinv, const int* __restrict__ row_ptr,
    const int* __restrict__ col, const float* __restrict__ W1,
    const float* __restrict__ b1, float* __restrict__ hA, int N, int nq, int nr) {
  __shared__ float sW[9 * 128];
  __shared__ float sx[256 * 9];
  __shared__ float sdi[256];           // per-row dinv for the GEMV-phase prescale
  int tid = threadIdx.x;
  for (int q = tid; q < 9 * 128; q += 256) sW[q] = W1[q];
  int i = blockIdx.x * 256 + tid;
  float4 A0, A1, A2, B0, B1, B2;
  A0 = A1 = A2 = B0 = B1 = B2 = make_float4(0.f, 0.f, 0.f, 0.f);
  float di = 0.0f;
  if (i < N) {
    di = dinv[i];
    const float4* xi = (const float4*)(xp + (size_t)i * 16);
    A0 = xi[0]; A1 = xi[1]; A2 = xi[2];   // self term: weight 1 in prescaled domain
    int rr = rankof(i, nq, nr);
    int rs = row_ptr[rr], re = row_ptr[rr + 1];
    int e = rs;
    for (; e + 2 <= re; e += 2) {        // x2 unroll: 6 independent 16B gathers in flight
      int c0 = __builtin_nontemporal_load(&col[e]);
      int c1 = __builtin_nontemporal_load(&col[e + 1]);
      const float4* q0 = (const float4*)(xp + (size_t)c0 * 16);
      const float4* q1 = (const float4*)(xp + (size_t)c1 * 16);
      float4 r0 = q0[0], r1 = q0[1], r2 = q0[2];
      float4 u0 = q1[0], u1 = q1[1], u2 = q1[2];
      A0.x += r0.x; A0.y += r0.y; A0.z += r0.z; A0.w += r0.w;
      A1.x += r1.x; A1.y += r1.y; A1.z += r1.z; A1.w += r1.w;
      A2.x += r2.x;
      B0.x += u0.x; B0.y += u0.y; B0.z += u0.z; B0.w += u0.w;
      B1.x += u1.x; B1.y += u1.y; B1.z += u1.z; B1.w += u1.w;
      B2.x += u2.x;
    }
    if (e < re) {
      int c0 = __builtin_nontemporal_load(&col[e]);
      const float4* q0 = (const float4*)(xp + (size_t)c0 * 16);
      float4 r0 = q0[0], r1 = q0[1], r2 = q0[2];
      A0.x += r0.x; A0.y += r0.y; A0.z += r0.z; A0.w += r0.w;
      A1.x += r1.x; A1.y += r1.y; A1.z += r1.z; A1.w += r1.w;
      A2.x += r2.x;
    }
  }
  sdi[tid] = di;
  float* so = sx + tid * 9;            // stride 9: worst 2-way alias (free)
  so[0] = (A0.x + B0.x) * di; so[1] = (A0.y + B0.y) * di; so[2] = (A0.z + B0.z) * di;
  so[3] = (A0.w + B0.w) * di; so[4] = (A1.x + B1.x) * di; so[5] = (A1.y + B1.y) * di;
  so[6] = (A1.z + B1.z) * di; so[7] = (A1.w + B1.w) * di; so[8] = (A2.x + B2.x) * di;
  __syncthreads();
  // GEMV phase: thread owns one output column; W1 column hoisted to registers.
  int cidx = tid & 127, rsub = tid >> 7;
  float w9[9];
#pragma unroll
  for (int f = 0; f < 9; ++f) w9[f] = sW[f * 128 + cidx];
  float bias = b1[cidx];
  int base = blockIdx.x * 256;
  for (int j = 0; j < 128; ++j) {
    int rl = j * 2 + rsub;             // wave-uniform -> sx reads broadcast
    int row = base + rl;
    if (row >= N) break;               // wave-uniform break
    float s = bias;
#pragma unroll
    for (int f = 0; f < 9; ++f) s = fmaf(sx[rl * 9 + f], w9[f], s);
    // PRESCALED store: dinv_row * relu(conv1) == relu(dinv_row * conv1), dinv>0
    hA[(size_t)row * 128 + cidx] = fmaxf(s, 0.0f) * sdi[rl];
  }
}

// ---------------- layer 2 aggregation: S = (A+I)-sum of prescaled-h1 rows ----------------
// half-wave float4 gathers, 8 edges/iter [r7/r9/r11: ~121 us, fabric floor]

__global__ __launch_bounds__(256) void aggH_kernel(const float* __restrict__ h,
    const int* __restrict__ row_ptr, const int* __restrict__ col,
    float* __restrict__ g, int N, int nq, int nr) {
  int wave = threadIdx.x >> 6;
  int lane = threadIdx.x & 63;
  int half = lane >> 5;                // each 32-lane half gathers one full 512B row
  int l32  = lane & 31;
  int i = blockIdx.x * 4 + wave;
  if (i >= N) return;                  // wave-uniform exit
  float4 self = *((const float4*)(h + (size_t)i * 128) + l32);
  float m = half ? 0.0f : 1.0f;        // self counted once (lower half)
  float4 a0 = make_float4(self.x * m, self.y * m, self.z * m, self.w * m);
  float4 a1 = make_float4(0.f, 0.f, 0.f, 0.f);
  float4 a2 = make_float4(0.f, 0.f, 0.f, 0.f);
  float4 a3 = make_float4(0.f, 0.f, 0.f, 0.f);
  int rr = rankof(i, nq, nr);
  int rs = row_ptr[rr], re = row_ptr[rr + 1];
  int e = rs;
  for (; e + 8 <= re; e += 8) {        // 8 edges/iter, 4 b128 gathers in flight per half
    int c0 = __builtin_nontemporal_load(&col[e + half]);
    int c1 = __builtin_nontemporal_load(&col[e + 2 + half]);
    int c2 = __builtin_nontemporal_load(&col[e + 4 + half]);
    int c3 = __builtin_nontemporal_load(&col[e + 6 + half]);
    float4 r0 = *((const float4*)(h + (size_t)c0 * 128) + l32);
    float4 r1 = *((const float4*)(h + (size_t)c1 * 128) + l32);
    float4 r2 = *((const float4*)(h + (size_t)c2 * 128) + l32);
    float4 r3 = *((const float4*)(h + (size_t)c3 * 128) + l32);
    a0.x += r0.x; a0.y += r0.y; a0.z += r0.z; a0.w += r0.w;
    a1.x += r1.x; a1.y += r1.y; a1.z += r1.z; a1.w += r1.w;
    a2.x += r2.x; a2.y += r2.y; a2.z += r2.z; a2.w += r2.w;
    a3.x += r3.x; a3.y += r3.y; a3.z += r3.z; a3.w += r3.w;
  }
  if (e + 4 <= re) {
    int c0 = __builtin_nontemporal_load(&col[e + half]);
    int c1 = __builtin_nontemporal_load(&col[e + 2 + half]);
    float4 r0 = *((const float4*)(h + (size_t)c0 * 128) + l32);
    float4 r1 = *((const float4*)(h + (size_t)c1 * 128) + l32);
    a0.x += r0.x; a0.y += r0.y; a0.z += r0.z; a0.w += r0.w;
    a1.x += r1.x; a1.y += r1.y; a1.z += r1.z; a1.w += r1.w;
    e += 4;
  }
  if (e + 2 <= re) {
    int c0 = __builtin_nontemporal_load(&col[e + half]);
    float4 r0 = *((const float4*)(h + (size_t)c0 * 128) + l32);
    a2.x += r0.x; a2.y += r0.y; a2.z += r0.z; a2.w += r0.w;
    e += 2;
  }
  if (e < re) {                        // odd tail: both halves take 0.5 (exact)
    int c0 = __builtin_nontemporal_load(&col[e]);
    float4 r0 = *((const float4*)(h + (size_t)c0 * 128) + l32);
    a3.x = fmaf(r0.x, 0.5f, a3.x); a3.y = fmaf(r0.y, 0.5f, a3.y);
    a3.z = fmaf(r0.z, 0.5f, a3.z); a3.w = fmaf(r0.w, 0.5f, a3.w);
  }
  float4 a = make_float4((a0.x + a1.x) + (a2.x + a3.x), (a0.y + a1.y) + (a2.y + a3.y),
                         (a0.z + a1.z) + (a2.z + a3.z), (a0.w + a1.w) + (a2.w + a3.w));
  a.x += __shfl_down(a.x, 32, 64);     // combine halves -> lanes 0..31 hold full row
  a.y += __shfl_down(a.y, 32, 64);
  a.z += __shfl_down(a.z, 32, 64);
  a.w += __shfl_down(a.w, 32, 64);
  if (half == 0) *((float4*)(g + (size_t)i * 128) + l32) = a;  // coalesced 512B store
}

// ---------------- fused layer-2/3 head: zd = dinv .* (relu(dinv.*(S@W2) + b2) @ v) ----------------

__global__ __launch_bounds__(256, 4) void gemmz_kernel(const float* __restrict__ g,
    const float* __restrict__ W2, const float* __restrict__ dinv,
    const float* __restrict__ b2, const float* __restrict__ v,
    float* __restrict__ zd, int N) {
  __shared__ float Hs[32 * 132];   // [k][row], stride 132
  __shared__ float Ws[32 * 128];   // [k][col]; reused as reduce scratch after
  int tid = threadIdx.x;
  int rb = blockIdx.x * 128;
  int tr = tid >> 4, tc = tid & 15;   // 16x16 threads; 8 rows x 8 cols each
  float acc[8][8];
#pragma unroll
  for (int r = 0; r < 8; ++r)
#pragma unroll
    for (int c = 0; c < 8; ++c) acc[r][c] = 0.0f;

  for (int kc = 0; kc < 128; kc += 32) {
#pragma unroll
    for (int j = 0; j < 4; ++j) {      // stage Hs transposed
      int q = tid + j * 256;
      int row = q >> 3;
      int kk = (q & 7) * 4;
      float4 vv = make_float4(0.f, 0.f, 0.f, 0.f);
      int grow = rb + row;
      if (grow < N) vv = *(const float4*)&g[(size_t)grow * 128 + kc + kk];
      Hs[(kk + 0) * 132 + row] = vv.x;
      Hs[(kk + 1) * 132 + row] = vv.y;
      Hs[(kk + 2) * 132 + row] = vv.z;
      Hs[(kk + 3) * 132 + row] = vv.w;
    }
#pragma unroll
    for (int j = 0; j < 4; ++j) {      // stage Ws
      int q = tid + j * 256;
      int kr = q >> 5;
      int c4 = (q & 31) * 4;
      *(float4*)&Ws[kr * 128 + c4] = *(const float4*)&W2[(size_t)(kc + kr) * 128 + c4];
    }
    __syncthreads();
#pragma unroll 4
    for (int kk = 0; kk < 32; ++kk) {
      float4 h0 = *(const float4*)&Hs[kk * 132 + tr * 8];
      float4 h1 = *(const float4*)&Hs[kk * 132 + tr * 8 + 4];
      float4 w0 = *(const float4*)&Ws[kk * 128 + tc * 8];
      float4 w1 = *(const float4*)&Ws[kk * 128 + tc * 8 + 4];
      float av[8] = {h0.x, h0.y, h0.z, h0.w, h1.x, h1.y, h1.z, h1.w};
      float bv[8] = {w0.x, w0.y, w0.z, w0.w, w1.x, w1.y, w1.z, w1.w};
#pragma unroll
      for (int r = 0; r < 8; ++r)
#pragma unroll
        for (int c = 0; c < 8; ++c) acc[r][c] = fmaf(av[r], bv[c], acc[r][c]);
    }
    __syncthreads();
  }
  // epilogue: t = dinv_row * acc; p_row = sum_c relu(t + b2_c) * v_c; reduce over tc
  float4 ba = *((const float4*)b2 + tc * 2);
  float4 bb = *((const float4*)b2 + tc * 2 + 1);
  float4 va = *((const float4*)v + tc * 2);
  float4 vb = *((const float4*)v + tc * 2 + 1);
  float bc[8] = {ba.x, ba.y, ba.z, ba.w, bb.x, bb.y, bb.z, bb.w};
  float vc[8] = {va.x, va.y, va.z, va.w, vb.x, vb.y, vb.z, vb.w};
  float* red = Ws;                     // safe: k-loop ended with __syncthreads()
#pragma unroll
  for (int r = 0; r < 8; ++r) {
    int row = rb + tr * 8 + r;
    float p = 0.0f;
    if (row < N) {
      float dr = dinv[row];
#pragma unroll
      for (int c = 0; c < 8; ++c)
        p += fmaxf(fmaf(dr, acc[r][c], bc[c]), 0.0f) * vc[c];
    }
    red[(tr * 8 + r) * 17 + tc] = p;
  }
  __syncthreads();
  if (tid < 128) {
    int row = rb + tid;
    if (row < N) {
      float s = 0.0f;
#pragma unroll
      for (int j = 0; j < 16; ++j) s += red[tid * 17 + j];
      zd[row] = dinv[row] * s;         // prescaled for layer-3 aggregation
    }
  }
}

// ---------------- layer 3 + mean-pool, edge-parallel on the raw edge list ----------------
// pool_g = sum_i dinv_i*zd_i*[b_i=g] + sum_e dinv[dst_e]*zd[src_e]*[b_dst=g].
// zd/dinv/batch are <1 MB total (L2-resident); edge reads are coalesced.

__global__ void pool_kernel(const float* __restrict__ zd, const float* __restrict__ dinv,
                            const int* __restrict__ src, const int* __restrict__ dst,
                            const int* __restrict__ batch,
                            float* gsum, float* gcnt, int E, int N) {
  __shared__ float lsum[64];
  __shared__ float lcnt[64];
  int t = threadIdx.x;
  if (t < 64) { lsum[t] = 0.0f; lcnt[t] = 0.0f; }
  __syncthreads();
  int e = blockIdx.x * blockDim.x + t;
  if (e < E) {
    int s = src[e], d = dst[e];
    atomicAdd(&lsum[batch[d]], dinv[d] * zd[s]);
  }
  if (e < N) {                         // self terms + counts (E > N covers all nodes)
    atomicAdd(&lsum[batch[e]], dinv[e] * zd[e]);
    atomicAdd(&lcnt[batch[e]], 1.0f);
  }
  __syncthreads();
  if (t < 64) {
    if (lsum[t] != 0.0f) atomicAdd(&gsum[t], lsum[t]);
    if (lcnt[t] != 0.0f) atomicAdd(&gcnt[t], lcnt[t]);
  }
}

__global__ void final_kernel(const float* __restrict__ gsum, const float* __restrict__ gcnt,
                             const float* __restrict__ c0, float* out, int G) {
  int g = threadIdx.x;
  if (g < G) out[g] = gsum[g] / fmaxf(gcnt[g], 1.0f) + c0[0];
}

// ---------------- launch ----------------

extern "C" void kernel_launch(void* const* d_in, const int* in_sizes, int n_in,
                              void* d_out, int out_size, void* d_ws, size_t ws_size,
                              hipStream_t stream) {
  const float* x      = (const float*)d_in[0];
  const int*   eidx   = (const int*)d_in[1];
  const int*   batch  = (const int*)d_in[2];
  const float* W1     = (const float*)d_in[3];
  const float* b1     = (const float*)d_in[4];
  const float* W2     = (const float*)d_in[5];
  const float* b2     = (const float*)d_in[6];
  const float* W3     = (const float*)d_in[7];
  const float* b3     = (const float*)d_in[8];
  const float* lin_w  = (const float*)d_in[9];
  const float* lin_b  = (const float*)d_in[10];
  float* out = (float*)d_out;

  int N = in_sizes[0] / 9;
  int E = in_sizes[1] / 2;
  int G = out_size;
  const int* src = eidx;
  const int* dst = eidx + E;
  int nq = N >> 3, nr = N & 7;         // rank(i) = (i&7)*nq + min(i&7,nr) + (i>>3)

  char* w = (char*)d_ws;
  size_t off = 0;
  auto alloc = [&](size_t bytes) -> void* {
    void* p = w + off;
    off += bytes;
    off = (off + 255) & ~(size_t)255;
    return p;
  };

  int nb = (N + 255) / 256;
  int nchunk = (E + CHUNK - 1) / CHUNK;
  // zero-init region (one memset): cursor (rank-space degree counts), gsum, gcnt
  int*   cursor = (int*)  alloc((size_t)N * 4);        // counts, then fill cursor (rank-indexed)
  float* gsum   = (float*)alloc(64 * 4);
  float* gcnt   = (float*)alloc(64 * 4);
  size_t zspan = off;
  float* dinv   = (float*)alloc((size_t)N * 4);
  int*   rowptr = (int*)  alloc((size_t)(N + 1) * 4);  // rank-indexed
  int*   bsum   = (int*)  alloc((size_t)nb * 4);
  int*   colsrc = (int*)  alloc((size_t)E * 4);        // CSR cols, class-contiguous regions
  float* hA     = (float*)alloc((size_t)N * 128 * 4);  // prescaled h1
  float* g      = (float*)alloc((size_t)N * 128 * 4);  // xp (N x 16) first, then S
  float* zd     = (float*)alloc((size_t)N * 4);
  float* v      = (float*)alloc(128 * 4);
  float* c0     = (float*)alloc(4);
  float* xp     = g;                                   // alias: dead before aggH writes g

  hipMemsetAsync(d_ws, 0, zspan, stream);
  deg_kernel<<<(E + 255) / 256, 256, 0, stream>>>(dst, cursor, E, nq, nr);
  dinv_bsum_pad_kernel<<<nb, 256, 0, stream>>>(cursor, dinv, bsum, x, xp, N, nq, nr);
  rowptr_vc0_kernel<<<nb, 256, 0, stream>>>(cursor, bsum, rowptr, cursor, N, E,
                                            W3, b3, lin_w, lin_b, v, c0);
  fill_part_kernel<<<nchunk * 8, 256, 0, stream>>>(src, dst, cursor, colsrc, E, nq, nr);
  agg9_gemm1_kernel<<<nb, 256, 0, stream>>>(xp, dinv, rowptr, colsrc, W1, b1, hA, N, nq, nr);
  aggH_kernel<<<(N + 3) / 4, 256, 0, stream>>>(hA, rowptr, colsrc, g, N, nq, nr);
  gemmz_kernel<<<(N + 127) / 128, 256, 0, stream>>>(g, W2, dinv, b2, v, zd, N);
  pool_kernel<<<(E + 255) / 256, 256, 0, stream>>>(zd, dinv, src, dst, batch, gsum, gcnt, E, N);
  final_kernel<<<1, 64, 0, stream>>>(gsum, gcnt, c0, out, G);
}

// Round 13
// 466.840 us; speedup vs baseline: 1.3091x; 1.3091x over previous
//
#include <hip/hip_runtime.h>
#include <math.h>

// Factorized GCN: A_hat = D^-1/2 (A+I) D^-1/2. All aggregations are
// prescale(rows by dinv) -> pure gather-sum over CSR cols -> postscale by dinv.
// CSR rows are RANK-PERMUTED by class c=i&7: rank(i) = base(c) + (i>>3), so
// each class's col region is contiguous and class-s fill blocks (-> XCD s via
// blockIdx%8) own their col lines exclusively.
// hA stores PRESCALED h1; xp rows are 16 floats (one aligned 64B line).
// aggH is the measured fabric floor: FETCH = 8 XCD x 51 MB compulsory, ~3.9 TB/s.
// Pooling is CSR per-node (r12's edge-parallel pool: 400k contended global
// atomics on 4 lines -> 156 us; reverted to 391-block CSR form).

#define CHUNK 2048

__device__ __forceinline__ int rankof(int i, int nq, int nr) {
  int c = i & 7;
  return c * nq + min(c, nr) + (i >> 3);
}

// ---------------- setup kernels ----------------

// single-pass int histogram in RANK space: cnt_rank[rank(dst)]++
__global__ void deg_kernel(const int* __restrict__ dst, int* cnt_rank,
                           int E, int nq, int nr) {
  int e = blockIdx.x * blockDim.x + threadIdx.x;
  if (e < E) atomicAdd(&cnt_rank[rankof(dst[e], nq, nr)], 1);
}

// dinv[i] = 1/sqrt(cnt_rank[rank(i)]+1); per-block RANK-ORDER sums -> bsum;
// xp = dinv_i * x_i padded to 16 floats (one 64B line per row)
__global__ void dinv_bsum_pad_kernel(const int* __restrict__ cnt_rank,
                                     float* __restrict__ dinv, int* bsum,
                                     const float* __restrict__ x,
                                     float* __restrict__ xp, int N, int nq, int nr) {
  __shared__ int s[256];
  int t = threadIdx.x;
  int gid = blockIdx.x * 256 + t;
  // bsum basis: coalesced read of the rank-array itself (scan is in rank space)
  s[t] = (gid < N) ? cnt_rank[gid] : 0;
  if (gid < N) {
    int c = cnt_rank[rankof(gid, nq, nr)];     // this node's in-degree
    float di = 1.0f / sqrtf((float)c + 1.0f);
    dinv[gid] = di;
    const float* xr = x + (size_t)gid * 9;
    float* xo = xp + (size_t)gid * 16;
    *(float4*)(xo + 0)  = make_float4(xr[0] * di, xr[1] * di, xr[2] * di, xr[3] * di);
    *(float4*)(xo + 4)  = make_float4(xr[4] * di, xr[5] * di, xr[6] * di, xr[7] * di);
    *(float4*)(xo + 8)  = make_float4(xr[8] * di, 0.0f, 0.0f, 0.0f);
    *(float4*)(xo + 12) = make_float4(0.0f, 0.0f, 0.0f, 0.0f);
  }
  __syncthreads();
  for (int off = 128; off > 0; off >>= 1) {
    if (t < off) s[t] += s[t + off];
    __syncthreads();
  }
  if (t == 0) bsum[blockIdx.x] = s[0];
}

// rowptr over RANK space: each block computes its own bsum-prefix. Block 0 also
// computes the collapsed head (v = W3@lin_w, c0 = b3.lin_w + lin_b).
// indeg/cursor alias (both rank-indexed): read-then-write safe.
__global__ void rowptr_vc0_kernel(const int* __restrict__ indeg, const int* __restrict__ bsum,
                                  int* row_ptr, int* cursor, int N, int E,
                                  const float* __restrict__ W3, const float* __restrict__ b3,
                                  const float* __restrict__ lin_w, const float* __restrict__ lin_b,
                                  float* v, float* c0) {
  __shared__ int ps[256];
  __shared__ int s[256];
  int t = threadIdx.x;
  int pref = 0;
  for (int q = t; q < blockIdx.x; q += 256) pref += bsum[q];
  ps[t] = pref;
  __syncthreads();
  for (int off = 128; off > 0; off >>= 1) {
    if (t < off) ps[t] += ps[t + off];
    __syncthreads();
  }
  int base = ps[0];
  int r = blockIdx.x * 256 + t;
  int val = (r < N) ? indeg[r] : 0;
  s[t] = val;
  __syncthreads();
  for (int off = 1; off < 256; off <<= 1) {
    int x = (t >= off) ? s[t - off] : 0;
    __syncthreads();
    s[t] += x;
    __syncthreads();
  }
  int excl = s[t] - val + base;
  if (r < N) { row_ptr[r] = excl; cursor[r] = excl; }
  if (blockIdx.x == 0) {
    if (t == 0) row_ptr[N] = E;
    if (t < 128) {
      float sv = 0.0f;
      for (int c = 0; c < 128; ++c) sv = fmaf(W3[t * 128 + c], lin_w[c], sv);
      v[t] = sv;
    } else if (t == 128) {
      float sv = 0.0f;
      for (int c = 0; c < 128; ++c) sv = fmaf(b3[c], lin_w[c], sv);
      c0[0] = sv + lin_b[0];
    }
  }
}

// partitioned CSR fill: dst&7-matched blocks write only their class's
// contiguous col region -> each 64B col line owned by exactly one XCD
__global__ __launch_bounds__(256) void fill_part_kernel(const int* __restrict__ src,
                                                        const int* __restrict__ dst,
                                                        int* cursor, int* __restrict__ col,
                                                        int E, int nq, int nr) {
  int sub = blockIdx.x & 7;
  int base = (blockIdx.x >> 3) * CHUNK;
#pragma unroll
  for (int j = 0; j < CHUNK / 256; ++j) {
    int e = base + j * 256 + threadIdx.x;
    if (e < E) {
      int d = dst[e];
      if ((d & 7) == sub) {
        int p = atomicAdd(&cursor[rankof(d, nq, nr)], 1);
        col[p] = src[e];
      }
    }
  }
}

// ---------------- layer 1 fused: xa = dinv_i * sum(xp), hA = dinv_i * relu(xa@W1+b1) ----------------
// Per-thread gather (256 independent chains/block), x2 edge unroll, 6 aligned
// 16B gathers in flight; each xp row is exactly one 64B line.

__global__ __launch_bounds__(256) void agg9_gemm1_kernel(const float* __restrict__ xp,
    const float* __restrict__ dinv, const int* __restrict__ row_ptr,
    const int* __restrict__ col, const float* __restrict__ W1,
    const float* __restrict__ b1, float* __restrict__ hA, int N, int nq, int nr) {
  __shared__ float sW[9 * 128];
  __shared__ float sx[256 * 9];
  __shared__ float sdi[256];           // per-row dinv for the GEMV-phase prescale
  int tid = threadIdx.x;
  for (int q = tid; q < 9 * 128; q += 256) sW[q] = W1[q];
  int i = blockIdx.x * 256 + tid;
  float4 A0, A1, A2, B0, B1, B2;
  A0 = A1 = A2 = B0 = B1 = B2 = make_float4(0.f, 0.f, 0.f, 0.f);
  float di = 0.0f;
  if (i < N) {
    di = dinv[i];
    const float4* xi = (const float4*)(xp + (size_t)i * 16);
    A0 = xi[0]; A1 = xi[1]; A2 = xi[2];   // self term: weight 1 in prescaled domain
    int rr = rankof(i, nq, nr);
    int rs = row_ptr[rr], re = row_ptr[rr + 1];
    int e = rs;
    for (; e + 2 <= re; e += 2) {        // x2 unroll: 6 independent 16B gathers in flight
      int c0 = __builtin_nontemporal_load(&col[e]);
      int c1 = __builtin_nontemporal_load(&col[e + 1]);
      const float4* q0 = (const float4*)(xp + (size_t)c0 * 16);
      const float4* q1 = (const float4*)(xp + (size_t)c1 * 16);
      float4 r0 = q0[0], r1 = q0[1], r2 = q0[2];
      float4 u0 = q1[0], u1 = q1[1], u2 = q1[2];
      A0.x += r0.x; A0.y += r0.y; A0.z += r0.z; A0.w += r0.w;
      A1.x += r1.x; A1.y += r1.y; A1.z += r1.z; A1.w += r1.w;
      A2.x += r2.x;
      B0.x += u0.x; B0.y += u0.y; B0.z += u0.z; B0.w += u0.w;
      B1.x += u1.x; B1.y += u1.y; B1.z += u1.z; B1.w += u1.w;
      B2.x += u2.x;
    }
    if (e < re) {
      int c0 = __builtin_nontemporal_load(&col[e]);
      const float4* q0 = (const float4*)(xp + (size_t)c0 * 16);
      float4 r0 = q0[0], r1 = q0[1], r2 = q0[2];
      A0.x += r0.x; A0.y += r0.y; A0.z += r0.z; A0.w += r0.w;
      A1.x += r1.x; A1.y += r1.y; A1.z += r1.z; A1.w += r1.w;
      A2.x += r2.x;
    }
  }
  sdi[tid] = di;
  float* so = sx + tid * 9;            // stride 9: worst 2-way alias (free)
  so[0] = (A0.x + B0.x) * di; so[1] = (A0.y + B0.y) * di; so[2] = (A0.z + B0.z) * di;
  so[3] = (A0.w + B0.w) * di; so[4] = (A1.x + B1.x) * di; so[5] = (A1.y + B1.y) * di;
  so[6] = (A1.z + B1.z) * di; so[7] = (A1.w + B1.w) * di; so[8] = (A2.x + B2.x) * di;
  __syncthreads();
  // GEMV phase: thread owns one output column; W1 column hoisted to registers.
  int cidx = tid & 127, rsub = tid >> 7;
  float w9[9];
#pragma unroll
  for (int f = 0; f < 9; ++f) w9[f] = sW[f * 128 + cidx];
  float bias = b1[cidx];
  int base = blockIdx.x * 256;
  for (int j = 0; j < 128; ++j) {
    int rl = j * 2 + rsub;             // wave-uniform -> sx reads broadcast
    int row = base + rl;
    if (row >= N) break;               // wave-uniform break
    float s = bias;
#pragma unroll
    for (int f = 0; f < 9; ++f) s = fmaf(sx[rl * 9 + f], w9[f], s);
    // PRESCALED store: dinv_row * relu(conv1) == relu(dinv_row * conv1), dinv>0
    hA[(size_t)row * 128 + cidx] = fmaxf(s, 0.0f) * sdi[rl];
  }
}

// ---------------- layer 2 aggregation: S = (A+I)-sum of prescaled-h1 rows ----------------
// half-wave float4 gathers, 8 edges/iter [r7/r9/r11: ~121 us, fabric floor]

__global__ __launch_bounds__(256) void aggH_kernel(const float* __restrict__ h,
    const int* __restrict__ row_ptr, const int* __restrict__ col,
    float* __restrict__ g, int N, int nq, int nr) {
  int wave = threadIdx.x >> 6;
  int lane = threadIdx.x & 63;
  int half = lane >> 5;                // each 32-lane half gathers one full 512B row
  int l32  = lane & 31;
  int i = blockIdx.x * 4 + wave;
  if (i >= N) return;                  // wave-uniform exit
  float4 self = *((const float4*)(h + (size_t)i * 128) + l32);
  float m = half ? 0.0f : 1.0f;        // self counted once (lower half)
  float4 a0 = make_float4(self.x * m, self.y * m, self.z * m, self.w * m);
  float4 a1 = make_float4(0.f, 0.f, 0.f, 0.f);
  float4 a2 = make_float4(0.f, 0.f, 0.f, 0.f);
  float4 a3 = make_float4(0.f, 0.f, 0.f, 0.f);
  int rr = rankof(i, nq, nr);
  int rs = row_ptr[rr], re = row_ptr[rr + 1];
  int e = rs;
  for (; e + 8 <= re; e += 8) {        // 8 edges/iter, 4 b128 gathers in flight per half
    int c0 = __builtin_nontemporal_load(&col[e + half]);
    int c1 = __builtin_nontemporal_load(&col[e + 2 + half]);
    int c2 = __builtin_nontemporal_load(&col[e + 4 + half]);
    int c3 = __builtin_nontemporal_load(&col[e + 6 + half]);
    float4 r0 = *((const float4*)(h + (size_t)c0 * 128) + l32);
    float4 r1 = *((const float4*)(h + (size_t)c1 * 128) + l32);
    float4 r2 = *((const float4*)(h + (size_t)c2 * 128) + l32);
    float4 r3 = *((const float4*)(h + (size_t)c3 * 128) + l32);
    a0.x += r0.x; a0.y += r0.y; a0.z += r0.z; a0.w += r0.w;
    a1.x += r1.x; a1.y += r1.y; a1.z += r1.z; a1.w += r1.w;
    a2.x += r2.x; a2.y += r2.y; a2.z += r2.z; a2.w += r2.w;
    a3.x += r3.x; a3.y += r3.y; a3.z += r3.z; a3.w += r3.w;
  }
  if (e + 4 <= re) {
    int c0 = __builtin_nontemporal_load(&col[e + half]);
    int c1 = __builtin_nontemporal_load(&col[e + 2 + half]);
    float4 r0 = *((const float4*)(h + (size_t)c0 * 128) + l32);
    float4 r1 = *((const float4*)(h + (size_t)c1 * 128) + l32);
    a0.x += r0.x; a0.y += r0.y; a0.z += r0.z; a0.w += r0.w;
    a1.x += r1.x; a1.y += r1.y; a1.z += r1.z; a1.w += r1.w;
    e += 4;
  }
  if (e + 2 <= re) {
    int c0 = __builtin_nontemporal_load(&col[e + half]);
    float4 r0 = *((const float4*)(h + (size_t)c0 * 128) + l32);
    a2.x += r0.x; a2.y += r0.y; a2.z += r0.z; a2.w += r0.w;
    e += 2;
  }
  if (e < re) {                        // odd tail: both halves take 0.5 (exact)
    int c0 = __builtin_nontemporal_load(&col[e]);
    float4 r0 = *((const float4*)(h + (size_t)c0 * 128) + l32);
    a3.x = fmaf(r0.x, 0.5f, a3.x); a3.y = fmaf(r0.y, 0.5f, a3.y);
    a3.z = fmaf(r0.z, 0.5f, a3.z); a3.w = fmaf(r0.w, 0.5f, a3.w);
  }
  float4 a = make_float4((a0.x + a1.x) + (a2.x + a3.x), (a0.y + a1.y) + (a2.y + a3.y),
                         (a0.z + a1.z) + (a2.z + a3.z), (a0.w + a1.w) + (a2.w + a3.w));
  a.x += __shfl_down(a.x, 32, 64);     // combine halves -> lanes 0..31 hold full row
  a.y += __shfl_down(a.y, 32, 64);
  a.z += __shfl_down(a.z, 32, 64);
  a.w += __shfl_down(a.w, 32, 64);
  if (half == 0) *((float4*)(g + (size_t)i * 128) + l32) = a;  // coalesced 512B store
}

// ---------------- fused layer-2/3 head: zd = dinv .* (relu(dinv.*(S@W2) + b2) @ v) ----------------

__global__ __launch_bounds__(256, 4) void gemmz_kernel(const float* __restrict__ g,
    const float* __restrict__ W2, const float* __restrict__ dinv,
    const float* __restrict__ b2, const float* __restrict__ v,
    float* __restrict__ zd, int N) {
  __shared__ float Hs[32 * 132];   // [k][row], stride 132
  __shared__ float Ws[32 * 128];   // [k][col]; reused as reduce scratch after
  int tid = threadIdx.x;
  int rb = blockIdx.x * 128;
  int tr = tid >> 4, tc = tid & 15;   // 16x16 threads; 8 rows x 8 cols each
  float acc[8][8];
#pragma unroll
  for (int r = 0; r < 8; ++r)
#pragma unroll
    for (int c = 0; c < 8; ++c) acc[r][c] = 0.0f;

  for (int kc = 0; kc < 128; kc += 32) {
#pragma unroll
    for (int j = 0; j < 4; ++j) {      // stage Hs transposed
      int q = tid + j * 256;
      int row = q >> 3;
      int kk = (q & 7) * 4;
      float4 vv = make_float4(0.f, 0.f, 0.f, 0.f);
      int grow = rb + row;
      if (grow < N) vv = *(const float4*)&g[(size_t)grow * 128 + kc + kk];
      Hs[(kk + 0) * 132 + row] = vv.x;
      Hs[(kk + 1) * 132 + row] = vv.y;
      Hs[(kk + 2) * 132 + row] = vv.z;
      Hs[(kk + 3) * 132 + row] = vv.w;
    }
#pragma unroll
    for (int j = 0; j < 4; ++j) {      // stage Ws
      int q = tid + j * 256;
      int kr = q >> 5;
      int c4 = (q & 31) * 4;
      *(float4*)&Ws[kr * 128 + c4] = *(const float4*)&W2[(size_t)(kc + kr) * 128 + c4];
    }
    __syncthreads();
#pragma unroll 4
    for (int kk = 0; kk < 32; ++kk) {
      float4 h0 = *(const float4*)&Hs[kk * 132 + tr * 8];
      float4 h1 = *(const float4*)&Hs[kk * 132 + tr * 8 + 4];
      float4 w0 = *(const float4*)&Ws[kk * 128 + tc * 8];
      float4 w1 = *(const float4*)&Ws[kk * 128 + tc * 8 + 4];
      float av[8] = {h0.x, h0.y, h0.z, h0.w, h1.x, h1.y, h1.z, h1.w};
      float bv[8] = {w0.x, w0.y, w0.z, w0.w, w1.x, w1.y, w1.z, w1.w};
#pragma unroll
      for (int r = 0; r < 8; ++r)
#pragma unroll
        for (int c = 0; c < 8; ++c) acc[r][c] = fmaf(av[r], bv[c], acc[r][c]);
    }
    __syncthreads();
  }
  // epilogue: t = dinv_row * acc; p_row = sum_c relu(t + b2_c) * v_c; reduce over tc
  float4 ba = *((const float4*)b2 + tc * 2);
  float4 bb = *((const float4*)b2 + tc * 2 + 1);
  float4 va = *((const float4*)v + tc * 2);
  float4 vb = *((const float4*)v + tc * 2 + 1);
  float bc[8] = {ba.x, ba.y, ba.z, ba.w, bb.x, bb.y, bb.z, bb.w};
  float vc[8] = {va.x, va.y, va.z, va.w, vb.x, vb.y, vb.z, vb.w};
  float* red = Ws;                     // safe: k-loop ended with __syncthreads()
#pragma unroll
  for (int r = 0; r < 8; ++r) {
    int row = rb + tr * 8 + r;
    float p = 0.0f;
    if (row < N) {
      float dr = dinv[row];
#pragma unroll
      for (int c = 0; c < 8; ++c)
        p += fmaxf(fmaf(dr, acc[r][c], bc[c]), 0.0f) * vc[c];
    }
    red[(tr * 8 + r) * 17 + tc] = p;
  }
  __syncthreads();
  if (tid < 128) {
    int row = rb + tid;
    if (row < N) {
      float s = 0.0f;
#pragma unroll
      for (int j = 0; j < 16; ++j) s += red[tid * 17 + j];
      zd[row] = dinv[row] * s;         // prescaled for layer-3 aggregation
    }
  }
}

// ---------------- layer 3 (scalar) aggregation + mean-pool binning ----------------
// CSR per-node: 391 blocks -> ~25k final global atomics (r12's edge-parallel
// form had 400k onto 4 lines -> 156 us; this form never showed in top-5).

__global__ void agg1_pool_kernel(const float* __restrict__ zd, const float* __restrict__ dinv,
    const int* __restrict__ row_ptr, const int* __restrict__ col,
    const int* __restrict__ batch, float* gsum, float* gcnt, int N, int nq, int nr) {
  __shared__ float lsum[64];
  __shared__ float lcnt[64];
  int t = threadIdx.x;
  if (t < 64) { lsum[t] = 0.0f; lcnt[t] = 0.0f; }
  __syncthreads();
  int i = blockIdx.x * blockDim.x + t;
  if (i < N) {
    float acc = zd[i];                 // self (weight 1 in prescaled domain)
    int rr = rankof(i, nq, nr);
    int rs = row_ptr[rr], re = row_ptr[rr + 1];
    int e = rs;
    for (; e + 4 <= re; e += 4) {      // x4 unroll: 4 scalar gathers in flight
      float z0 = zd[col[e]], z1 = zd[col[e + 1]];
      float z2 = zd[col[e + 2]], z3 = zd[col[e + 3]];
      acc += (z0 + z1) + (z2 + z3);
    }
    for (; e < re; ++e) acc += zd[col[e]];
    acc *= dinv[i];
    int gidx = batch[i];
    atomicAdd(&lsum[gidx], acc);
    atomicAdd(&lcnt[gidx], 1.0f);
  }
  __syncthreads();
  if (t < 64) {
    if (lsum[t] != 0.0f) atomicAdd(&gsum[t], lsum[t]);
    if (lcnt[t] != 0.0f) atomicAdd(&gcnt[t], lcnt[t]);
  }
}

__global__ void final_kernel(const float* __restrict__ gsum, const float* __restrict__ gcnt,
                             const float* __restrict__ c0, float* out, int G) {
  int g = threadIdx.x;
  if (g < G) out[g] = gsum[g] / fmaxf(gcnt[g], 1.0f) + c0[0];
}

// ---------------- launch ----------------

extern "C" void kernel_launch(void* const* d_in, const int* in_sizes, int n_in,
                              void* d_out, int out_size, void* d_ws, size_t ws_size,
                              hipStream_t stream) {
  const float* x      = (const float*)d_in[0];
  const int*   eidx   = (const int*)d_in[1];
  const int*   batch  = (const int*)d_in[2];
  const float* W1     = (const float*)d_in[3];
  const float* b1     = (const float*)d_in[4];
  const float* W2     = (const float*)d_in[5];
  const float* b2     = (const float*)d_in[6];
  const float* W3     = (const float*)d_in[7];
  const float* b3     = (const float*)d_in[8];
  const float* lin_w  = (const float*)d_in[9];
  const float* lin_b  = (const float*)d_in[10];
  float* out = (float*)d_out;

  int N = in_sizes[0] / 9;
  int E = in_sizes[1] / 2;
  int G = out_size;
  const int* src = eidx;
  const int* dst = eidx + E;
  int nq = N >> 3, nr = N & 7;         // rank(i) = (i&7)*nq + min(i&7,nr) + (i>>3)

  char* w = (char*)d_ws;
  size_t off = 0;
  auto alloc = [&](size_t bytes) -> void* {
    void* p = w + off;
    off += bytes;
    off = (off + 255) & ~(size_t)255;
    return p;
  };

  int nb = (N + 255) / 256;
  int nchunk = (E + CHUNK - 1) / CHUNK;
  // zero-init region (one memset): cursor (rank-space degree counts), gsum, gcnt
  int*   cursor = (int*)  alloc((size_t)N * 4);        // counts, then fill cursor (rank-indexed)
  float* gsum   = (float*)alloc(64 * 4);
  float* gcnt   = (float*)alloc(64 * 4);
  size_t zspan = off;
  float* dinv   = (float*)alloc((size_t)N * 4);
  int*   rowptr = (int*)  alloc((size_t)(N + 1) * 4);  // rank-indexed
  int*   bsum   = (int*)  alloc((size_t)nb * 4);
  int*   colsrc = (int*)  alloc((size_t)E * 4);        // CSR cols, class-contiguous regions
  float* hA     = (float*)alloc((size_t)N * 128 * 4);  // prescaled h1
  float* g      = (float*)alloc((size_t)N * 128 * 4);  // xp (N x 16) first, then S
  float* zd     = (float*)alloc((size_t)N * 4);
  float* v      = (float*)alloc(128 * 4);
  float* c0     = (float*)alloc(4);
  float* xp     = g;                                   // alias: dead before aggH writes g

  hipMemsetAsync(d_ws, 0, zspan, stream);
  deg_kernel<<<(E + 255) / 256, 256, 0, stream>>>(dst, cursor, E, nq, nr);
  dinv_bsum_pad_kernel<<<nb, 256, 0, stream>>>(cursor, dinv, bsum, x, xp, N, nq, nr);
  rowptr_vc0_kernel<<<nb, 256, 0, stream>>>(cursor, bsum, rowptr, cursor, N, E,
                                            W3, b3, lin_w, lin_b, v, c0);
  fill_part_kernel<<<nchunk * 8, 256, 0, stream>>>(src, dst, cursor, colsrc, E, nq, nr);
  agg9_gemm1_kernel<<<nb, 256, 0, stream>>>(xp, dinv, rowptr, colsrc, W1, b1, hA, N, nq, nr);
  aggH_kernel<<<(N + 3) / 4, 256, 0, stream>>>(hA, rowptr, colsrc, g, N, nq, nr);
  gemmz_kernel<<<(N + 127) / 128, 256, 0, stream>>>(g, W2, dinv, b2, v, zd, N);
  agg1_pool_kernel<<<nb, 256, 0, stream>>>(zd, dinv, rowptr, colsrc, batch, gsum, gcnt, N, nq, nr);
  final_kernel<<<1, 64, 0, stream>>>(gsum, gcnt, c0, out, G);
}

// Round 14
// 409.835 us; speedup vs baseline: 1.4912x; 1.1391x over previous
//
#include <hip/hip_runtime.h>
#include <math.h>

// Factorized GCN: A_hat = D^-1/2 (A+I) D^-1/2. All aggregations are
// prescale(rows by dinv) -> pure gather-sum over CSR cols -> postscale by dinv.
// CSR rows are RANK-PERMUTED by class c=i&7 (class-contiguous col regions ->
// fill's col lines owned by one XCD). Node-indexed rows[i]=(rs,re) int2 kills
// the scattered rank lookup in the gather kernels (r13: +6.5MB FETCH in aggH).
// hA (prescaled h1) is BF16: halves aggH's compulsory FETCH floor
// (8 XCD x footprint). All accumulation stays fp32; only the gathered
// operand is bf16 (error budget ~1e-6 at output vs 3.2e-5 threshold).

#define CHUNK 2048

__device__ __forceinline__ int rankof(int i, int nq, int nr) {
  int c = i & 7;
  return c * nq + min(c, nr) + (i >> 3);
}
__device__ __forceinline__ unsigned short f2bf(float f) {   // RNE
  unsigned int u = __float_as_uint(f);
  return (unsigned short)((u + 0x7fff + ((u >> 16) & 1)) >> 16);
}
__device__ __forceinline__ float bflo(unsigned int u) { return __uint_as_float(u << 16); }
__device__ __forceinline__ float bfhi(unsigned int u) { return __uint_as_float(u & 0xffff0000u); }

// ---------------- setup kernels ----------------

// single-pass int histogram in RANK space: cnt_rank[rank(dst)]++
__global__ void deg_kernel(const int* __restrict__ dst, int* cnt_rank,
                           int E, int nq, int nr) {
  int e = blockIdx.x * blockDim.x + threadIdx.x;
  if (e < E) atomicAdd(&cnt_rank[rankof(dst[e], nq, nr)], 1);
}

// dinv[i] = 1/sqrt(cnt_rank[rank(i)]+1); per-block RANK-ORDER sums -> bsum;
// xp = dinv_i * x_i padded to 16 floats (one 64B line per row)
__global__ void dinv_bsum_pad_kernel(const int* __restrict__ cnt_rank,
                                     float* __restrict__ dinv, int* bsum,
                                     const float* __restrict__ x,
                                     float* __restrict__ xp, int N, int nq, int nr) {
  __shared__ int s[256];
  int t = threadIdx.x;
  int gid = blockIdx.x * 256 + t;
  s[t] = (gid < N) ? cnt_rank[gid] : 0;     // scan basis: rank-order, coalesced
  if (gid < N) {
    int c = cnt_rank[rankof(gid, nq, nr)];  // this node's in-degree
    float di = 1.0f / sqrtf((float)c + 1.0f);
    dinv[gid] = di;
    const float* xr = x + (size_t)gid * 9;
    float* xo = xp + (size_t)gid * 16;
    *(float4*)(xo + 0)  = make_float4(xr[0] * di, xr[1] * di, xr[2] * di, xr[3] * di);
    *(float4*)(xo + 4)  = make_float4(xr[4] * di, xr[5] * di, xr[6] * di, xr[7] * di);
    *(float4*)(xo + 8)  = make_float4(xr[8] * di, 0.0f, 0.0f, 0.0f);
    *(float4*)(xo + 12) = make_float4(0.0f, 0.0f, 0.0f, 0.0f);
  }
  __syncthreads();
  for (int off = 128; off > 0; off >>= 1) {
    if (t < off) s[t] += s[t + off];
    __syncthreads();
  }
  if (t == 0) bsum[blockIdx.x] = s[0];
}

// Scan over RANK space; emits rank-indexed cursor (for fill) and NODE-indexed
// rows[i] = (rs, re) for the gather kernels. Block 0 computes the collapsed
// head (v = W3@lin_w, c0 = b3.lin_w + lin_b). indeg/cursor alias: safe.
__global__ void rowptr_vc0_kernel(const int* __restrict__ indeg, const int* __restrict__ bsum,
                                  int2* __restrict__ rows, int* cursor, int N, int E,
                                  int nq, int nr,
                                  const float* __restrict__ W3, const float* __restrict__ b3,
                                  const float* __restrict__ lin_w, const float* __restrict__ lin_b,
                                  float* v, float* c0) {
  __shared__ int ps[256];
  __shared__ int s[256];
  int t = threadIdx.x;
  int pref = 0;
  for (int q = t; q < blockIdx.x; q += 256) pref += bsum[q];
  ps[t] = pref;
  __syncthreads();
  for (int off = 128; off > 0; off >>= 1) {
    if (t < off) ps[t] += ps[t + off];
    __syncthreads();
  }
  int base = ps[0];
  int r = blockIdx.x * 256 + t;
  int val = (r < N) ? indeg[r] : 0;
  s[t] = val;
  __syncthreads();
  for (int off = 1; off < 256; off <<= 1) {
    int x = (t >= off) ? s[t - off] : 0;
    __syncthreads();
    s[t] += x;
    __syncthreads();
  }
  int excl = s[t] - val + base;
  if (r < N) {
    cursor[r] = excl;                       // rank-indexed fill cursor
    int c = 0;                              // invert rank -> node id
#pragma unroll
    for (int cc = 1; cc < 8; ++cc) {
      int b = cc * nq + min(cc, nr);
      if (r >= b) c = cc;
    }
    int iinv = ((r - (c * nq + min(c, nr))) << 3) | c;
    rows[iinv] = make_int2(excl, excl + val);  // node-indexed (scattered, once)
  }
  if (blockIdx.x == 0) {
    if (t < 128) {
      float sv = 0.0f;
      for (int c = 0; c < 128; ++c) sv = fmaf(W3[t * 128 + c], lin_w[c], sv);
      v[t] = sv;
    } else if (t == 128) {
      float sv = 0.0f;
      for (int c = 0; c < 128; ++c) sv = fmaf(b3[c], lin_w[c], sv);
      c0[0] = sv + lin_b[0];
    }
  }
}

// partitioned CSR fill: dst&7-matched blocks write only their class's
// contiguous col region -> each 64B col line owned by exactly one XCD
__global__ __launch_bounds__(256) void fill_part_kernel(const int* __restrict__ src,
                                                        const int* __restrict__ dst,
                                                        int* cursor, int* __restrict__ col,
                                                        int E, int nq, int nr) {
  int sub = blockIdx.x & 7;
  int base = (blockIdx.x >> 3) * CHUNK;
#pragma unroll
  for (int j = 0; j < CHUNK / 256; ++j) {
    int e = base + j * 256 + threadIdx.x;
    if (e < E) {
      int d = dst[e];
      if ((d & 7) == sub) {
        int p = atomicAdd(&cursor[rankof(d, nq, nr)], 1);
        col[p] = src[e];
      }
    }
  }
}

// ---------------- layer 1 fused: xa = dinv_i * sum(xp), hA = bf16(dinv_i * relu(xa@W1+b1)) ----------------
// Per-thread gather (256 independent chains/block), x2 edge unroll, 6 aligned
// 16B gathers in flight; each xp row is exactly one 64B line.

__global__ __launch_bounds__(256) void agg9_gemm1_kernel(const float* __restrict__ xp,
    const float* __restrict__ dinv, const int2* __restrict__ rows,
    const int* __restrict__ col, const float* __restrict__ W1,
    const float* __restrict__ b1, unsigned short* __restrict__ hA, int N) {
  __shared__ float sW[9 * 128];
  __shared__ float sx[256 * 9];
  __shared__ float sdi[256];           // per-row dinv for the GEMV-phase prescale
  int tid = threadIdx.x;
  for (int q = tid; q < 9 * 128; q += 256) sW[q] = W1[q];
  int i = blockIdx.x * 256 + tid;
  float4 A0, A1, A2, B0, B1, B2;
  A0 = A1 = A2 = B0 = B1 = B2 = make_float4(0.f, 0.f, 0.f, 0.f);
  float di = 0.0f;
  if (i < N) {
    di = dinv[i];
    const float4* xi = (const float4*)(xp + (size_t)i * 16);
    A0 = xi[0]; A1 = xi[1]; A2 = xi[2];   // self term: weight 1 in prescaled domain
    int2 rw = rows[i];
    int rs = rw.x, re = rw.y;
    int e = rs;
    for (; e + 2 <= re; e += 2) {        // x2 unroll: 6 independent 16B gathers in flight
      int c0 = __builtin_nontemporal_load(&col[e]);
      int c1 = __builtin_nontemporal_load(&col[e + 1]);
      const float4* q0 = (const float4*)(xp + (size_t)c0 * 16);
      const float4* q1 = (const float4*)(xp + (size_t)c1 * 16);
      float4 r0 = q0[0], r1 = q0[1], r2 = q0[2];
      float4 u0 = q1[0], u1 = q1[1], u2 = q1[2];
      A0.x += r0.x; A0.y += r0.y; A0.z += r0.z; A0.w += r0.w;
      A1.x += r1.x; A1.y += r1.y; A1.z += r1.z; A1.w += r1.w;
      A2.x += r2.x;
      B0.x += u0.x; B0.y += u0.y; B0.z += u0.z; B0.w += u0.w;
      B1.x += u1.x; B1.y += u1.y; B1.z += u1.z; B1.w += u1.w;
      B2.x += u2.x;
    }
    if (e < re) {
      int c0 = __builtin_nontemporal_load(&col[e]);
      const float4* q0 = (const float4*)(xp + (size_t)c0 * 16);
      float4 r0 = q0[0], r1 = q0[1], r2 = q0[2];
      A0.x += r0.x; A0.y += r0.y; A0.z += r0.z; A0.w += r0.w;
      A1.x += r1.x; A1.y += r1.y; A1.z += r1.z; A1.w += r1.w;
      A2.x += r2.x;
    }
  }
  sdi[tid] = di;
  float* so = sx + tid * 9;            // stride 9: worst 2-way alias (free)
  so[0] = (A0.x + B0.x) * di; so[1] = (A0.y + B0.y) * di; so[2] = (A0.z + B0.z) * di;
  so[3] = (A0.w + B0.w) * di; so[4] = (A1.x + B1.x) * di; so[5] = (A1.y + B1.y) * di;
  so[6] = (A1.z + B1.z) * di; so[7] = (A1.w + B1.w) * di; so[8] = (A2.x + B2.x) * di;
  __syncthreads();
  // GEMV phase: thread owns TWO adjacent output columns -> one packed 4B store.
  int c2 = tid & 63, rsub = tid >> 6;   // 64 col-pairs x 4 row-slots
  float wA[9], wB[9];
#pragma unroll
  for (int f = 0; f < 9; ++f) {
    wA[f] = sW[f * 128 + 2 * c2];
    wB[f] = sW[f * 128 + 2 * c2 + 1];
  }
  float biasA = b1[2 * c2], biasB = b1[2 * c2 + 1];
  int base = blockIdx.x * 256;
  for (int j = 0; j < 64; ++j) {
    int rl = j * 4 + rsub;             // wave-uniform -> sx reads broadcast
    int row = base + rl;
    if (row >= N) break;               // wave-uniform break
    float sA = biasA, sB = biasB;
#pragma unroll
    for (int f = 0; f < 9; ++f) {
      float xv = sx[rl * 9 + f];
      sA = fmaf(xv, wA[f], sA);
      sB = fmaf(xv, wB[f], sB);
    }
    float d = sdi[rl];
    // PRESCALED bf16 store: dinv*relu(conv1) == relu(dinv*conv1), dinv>0
    unsigned int pk = (unsigned int)f2bf(fmaxf(sA, 0.0f) * d)
                    | ((unsigned int)f2bf(fmaxf(sB, 0.0f) * d) << 16);
    *(unsigned int*)(hA + (size_t)row * 128 + 2 * c2) = pk;
  }
}

// ---------------- layer 2 aggregation: S = (A+I)-sum of prescaled-h1 rows (bf16 in, fp32 acc) ----------------
// half-wave gathers: 32 lanes x 8B (uint2 = 4 bf16) = one full 256B row/edge.

__global__ __launch_bounds__(256) void aggH_kernel(const unsigned short* __restrict__ h,
    const int2* __restrict__ rows, const int* __restrict__ col,
    float* __restrict__ g, int N) {
  int wave = threadIdx.x >> 6;
  int lane = threadIdx.x & 63;
  int half = lane >> 5;                // each 32-lane half gathers one full row
  int l32  = lane & 31;
  int i = blockIdx.x * 4 + wave;
  if (i >= N) return;                  // wave-uniform exit
  uint2 sp = *((const uint2*)(h + (size_t)i * 128) + l32);
  float m = half ? 0.0f : 1.0f;        // self counted once (lower half)
  float4 a0 = make_float4(bflo(sp.x) * m, bfhi(sp.x) * m, bflo(sp.y) * m, bfhi(sp.y) * m);
  float4 a1 = make_float4(0.f, 0.f, 0.f, 0.f);
  float4 a2 = make_float4(0.f, 0.f, 0.f, 0.f);
  float4 a3 = make_float4(0.f, 0.f, 0.f, 0.f);
  int2 rw = rows[i];
  int rs = rw.x, re = rw.y;
  int e = rs;
  for (; e + 8 <= re; e += 8) {        // 8 edges/iter, 4 gathers in flight per half
    int c0 = __builtin_nontemporal_load(&col[e + half]);
    int c1 = __builtin_nontemporal_load(&col[e + 2 + half]);
    int c2 = __builtin_nontemporal_load(&col[e + 4 + half]);
    int c3 = __builtin_nontemporal_load(&col[e + 6 + half]);
    uint2 p0 = *((const uint2*)(h + (size_t)c0 * 128) + l32);
    uint2 p1 = *((const uint2*)(h + (size_t)c1 * 128) + l32);
    uint2 p2 = *((const uint2*)(h + (size_t)c2 * 128) + l32);
    uint2 p3 = *((const uint2*)(h + (size_t)c3 * 128) + l32);
    a0.x += bflo(p0.x); a0.y += bfhi(p0.x); a0.z += bflo(p0.y); a0.w += bfhi(p0.y);
    a1.x += bflo(p1.x); a1.y += bfhi(p1.x); a1.z += bflo(p1.y); a1.w += bfhi(p1.y);
    a2.x += bflo(p2.x); a2.y += bfhi(p2.x); a2.z += bflo(p2.y); a2.w += bfhi(p2.y);
    a3.x += bflo(p3.x); a3.y += bfhi(p3.x); a3.z += bflo(p3.y); a3.w += bfhi(p3.y);
  }
  if (e + 4 <= re) {
    int c0 = __builtin_nontemporal_load(&col[e + half]);
    int c1 = __builtin_nontemporal_load(&col[e + 2 + half]);
    uint2 p0 = *((const uint2*)(h + (size_t)c0 * 128) + l32);
    uint2 p1 = *((const uint2*)(h + (size_t)c1 * 128) + l32);
    a0.x += bflo(p0.x); a0.y += bfhi(p0.x); a0.z += bflo(p0.y); a0.w += bfhi(p0.y);
    a1.x += bflo(p1.x); a1.y += bfhi(p1.x); a1.z += bflo(p1.y); a1.w += bfhi(p1.y);
    e += 4;
  }
  if (e + 2 <= re) {
    int c0 = __builtin_nontemporal_load(&col[e + half]);
    uint2 p0 = *((const uint2*)(h + (size_t)c0 * 128) + l32);
    a2.x += bflo(p0.x); a2.y += bfhi(p0.x); a2.z += bflo(p0.y); a2.w += bfhi(p0.y);
    e += 2;
  }
  if (e < re) {                        // odd tail: both halves take 0.5 (exact)
    int c0 = __builtin_nontemporal_load(&col[e]);
    uint2 p0 = *((const uint2*)(h + (size_t)c0 * 128) + l32);
    a3.x = fmaf(bflo(p0.x), 0.5f, a3.x); a3.y = fmaf(bfhi(p0.x), 0.5f, a3.y);
    a3.z = fmaf(bflo(p0.y), 0.5f, a3.z); a3.w = fmaf(bfhi(p0.y), 0.5f, a3.w);
  }
  float4 a = make_float4((a0.x + a1.x) + (a2.x + a3.x), (a0.y + a1.y) + (a2.y + a3.y),
                         (a0.z + a1.z) + (a2.z + a3.z), (a0.w + a1.w) + (a2.w + a3.w));
  a.x += __shfl_down(a.x, 32, 64);     // combine halves -> lanes 0..31 hold full row
  a.y += __shfl_down(a.y, 32, 64);
  a.z += __shfl_down(a.z, 32, 64);
  a.w += __shfl_down(a.w, 32, 64);
  if (half == 0) *((float4*)(g + (size_t)i * 128) + l32) = a;  // coalesced 512B store
}

// ---------------- fused layer-2/3 head: zd = dinv .* (relu(dinv.*(S@W2) + b2) @ v) ----------------

__global__ __launch_bounds__(256, 4) void gemmz_kernel(const float* __restrict__ g,
    const float* __restrict__ W2, const float* __restrict__ dinv,
    const float* __restrict__ b2, const float* __restrict__ v,
    float* __restrict__ zd, int N) {
  __shared__ float Hs[32 * 132];   // [k][row], stride 132
  __shared__ float Ws[32 * 128];   // [k][col]; reused as reduce scratch after
  int tid = threadIdx.x;
  int rb = blockIdx.x * 128;
  int tr = tid >> 4, tc = tid & 15;   // 16x16 threads; 8 rows x 8 cols each
  float acc[8][8];
#pragma unroll
  for (int r = 0; r < 8; ++r)
#pragma unroll
    for (int c = 0; c < 8; ++c) acc[r][c] = 0.0f;

  for (int kc = 0; kc < 128; kc += 32) {
#pragma unroll
    for (int j = 0; j < 4; ++j) {      // stage Hs transposed
      int q = tid + j * 256;
      int row = q >> 3;
      int kk = (q & 7) * 4;
      float4 vv = make_float4(0.f, 0.f, 0.f, 0.f);
      int grow = rb + row;
      if (grow < N) vv = *(const float4*)&g[(size_t)grow * 128 + kc + kk];
      Hs[(kk + 0) * 132 + row] = vv.x;
      Hs[(kk + 1) * 132 + row] = vv.y;
      Hs[(kk + 2) * 132 + row] = vv.z;
      Hs[(kk + 3) * 132 + row] = vv.w;
    }
#pragma unroll
    for (int j = 0; j < 4; ++j) {      // stage Ws
      int q = tid + j * 256;
      int kr = q >> 5;
      int c4 = (q & 31) * 4;
      *(float4*)&Ws[kr * 128 + c4] = *(const float4*)&W2[(size_t)(kc + kr) * 128 + c4];
    }
    __syncthreads();
#pragma unroll 4
    for (int kk = 0; kk < 32; ++kk) {
      float4 h0 = *(const float4*)&Hs[kk * 132 + tr * 8];
      float4 h1 = *(const float4*)&Hs[kk * 132 + tr * 8 + 4];
      float4 w0 = *(const float4*)&Ws[kk * 128 + tc * 8];
      float4 w1 = *(const float4*)&Ws[kk * 128 + tc * 8 + 4];
      float av[8] = {h0.x, h0.y, h0.z, h0.w, h1.x, h1.y, h1.z, h1.w};
      float bv[8] = {w0.x, w0.y, w0.z, w0.w, w1.x, w1.y, w1.z, w1.w};
#pragma unroll
      for (int r = 0; r < 8; ++r)
#pragma unroll
        for (int c = 0; c < 8; ++c) acc[r][c] = fmaf(av[r], bv[c], acc[r][c]);
    }
    __syncthreads();
  }
  // epilogue: t = dinv_row * acc; p_row = sum_c relu(t + b2_c) * v_c; reduce over tc
  float4 ba = *((const float4*)b2 + tc * 2);
  float4 bb = *((const float4*)b2 + tc * 2 + 1);
  float4 va = *((const float4*)v + tc * 2);
  float4 vb = *((const float4*)v + tc * 2 + 1);
  float bc[8] = {ba.x, ba.y, ba.z, ba.w, bb.x, bb.y, bb.z, bb.w};
  float vc[8] = {va.x, va.y, va.z, va.w, vb.x, vb.y, vb.z, vb.w};
  float* red = Ws;                     // safe: k-loop ended with __syncthreads()
#pragma unroll
  for (int r = 0; r < 8; ++r) {
    int row = rb + tr * 8 + r;
    float p = 0.0f;
    if (row < N) {
      float dr = dinv[row];
#pragma unroll
      for (int c = 0; c < 8; ++c)
        p += fmaxf(fmaf(dr, acc[r][c], bc[c]), 0.0f) * vc[c];
    }
    red[(tr * 8 + r) * 17 + tc] = p;
  }
  __syncthreads();
  if (tid < 128) {
    int row = rb + tid;
    if (row < N) {
      float s = 0.0f;
#pragma unroll
      for (int j = 0; j < 16; ++j) s += red[tid * 17 + j];
      zd[row] = dinv[row] * s;         // prescaled for layer-3 aggregation
    }
  }
}

// ---------------- layer 3 (scalar) aggregation + mean-pool binning ----------------
// CSR per-node: 391 blocks -> ~25k final global atomics (r12's edge-parallel
// form: 400k atomics on 4 lines -> 156 us; never again).

__global__ void agg1_pool_kernel(const float* __restrict__ zd, const float* __restrict__ dinv,
    const int2* __restrict__ rows, const int* __restrict__ col,
    const int* __restrict__ batch, float* gsum, float* gcnt, int N) {
  __shared__ float lsum[64];
  __shared__ float lcnt[64];
  int t = threadIdx.x;
  if (t < 64) { lsum[t] = 0.0f; lcnt[t] = 0.0f; }
  __syncthreads();
  int i = blockIdx.x * blockDim.x + t;
  if (i < N) {
    float acc = zd[i];                 // self (weight 1 in prescaled domain)
    int2 rw = rows[i];
    int rs = rw.x, re = rw.y;
    int e = rs;
    for (; e + 4 <= re; e += 4) {      // x4 unroll: 4 scalar gathers in flight
      float z0 = zd[col[e]], z1 = zd[col[e + 1]];
      float z2 = zd[col[e + 2]], z3 = zd[col[e + 3]];
      acc += (z0 + z1) + (z2 + z3);
    }
    for (; e < re; ++e) acc += zd[col[e]];
    acc *= dinv[i];
    int gidx = batch[i];
    atomicAdd(&lsum[gidx], acc);
    atomicAdd(&lcnt[gidx], 1.0f);
  }
  __syncthreads();
  if (t < 64) {
    if (lsum[t] != 0.0f) atomicAdd(&gsum[t], lsum[t]);
    if (lcnt[t] != 0.0f) atomicAdd(&gcnt[t], lcnt[t]);
  }
}

__global__ void final_kernel(const float* __restrict__ gsum, const float* __restrict__ gcnt,
                             const float* __restrict__ c0, float* out, int G) {
  int g = threadIdx.x;
  if (g < G) out[g] = gsum[g] / fmaxf(gcnt[g], 1.0f) + c0[0];
}

// ---------------- launch ----------------

extern "C" void kernel_launch(void* const* d_in, const int* in_sizes, int n_in,
                              void* d_out, int out_size, void* d_ws, size_t ws_size,
                              hipStream_t stream) {
  const float* x      = (const float*)d_in[0];
  const int*   eidx   = (const int*)d_in[1];
  const int*   batch  = (const int*)d_in[2];
  const float* W1     = (const float*)d_in[3];
  const float* b1     = (const float*)d_in[4];
  const float* W2     = (const float*)d_in[5];
  const float* b2     = (const float*)d_in[6];
  const float* W3     = (const float*)d_in[7];
  const float* b3     = (const float*)d_in[8];
  const float* lin_w  = (const float*)d_in[9];
  const float* lin_b  = (const float*)d_in[10];
  float* out = (float*)d_out;

  int N = in_sizes[0] / 9;
  int E = in_sizes[1] / 2;
  int G = out_size;
  const int* src = eidx;
  const int* dst = eidx + E;
  int nq = N >> 3, nr = N & 7;         // rank(i) = (i&7)*nq + min(i&7,nr) + (i>>3)

  char* w = (char*)d_ws;
  size_t off = 0;
  auto alloc = [&](size_t bytes) -> void* {
    void* p = w + off;
    off += bytes;
    off = (off + 255) & ~(size_t)255;
    return p;
  };

  int nb = (N + 255) / 256;
  int nchunk = (E + CHUNK - 1) / CHUNK;
  // zero-init region (one memset): cursor (rank-space degree counts), gsum, gcnt
  int*   cursor = (int*)  alloc((size_t)N * 4);        // counts, then fill cursor (rank-indexed)
  float* gsum   = (float*)alloc(64 * 4);
  float* gcnt   = (float*)alloc(64 * 4);
  size_t zspan = off;
  float* dinv   = (float*)alloc((size_t)N * 4);
  int2*  rows   = (int2*) alloc((size_t)N * 8);        // node-indexed (rs,re)
  int*   bsum   = (int*)  alloc((size_t)nb * 4);
  int*   colsrc = (int*)  alloc((size_t)E * 4);        // CSR cols, class-contiguous regions
  unsigned short* hA = (unsigned short*)alloc((size_t)N * 128 * 2);  // prescaled h1, BF16
  float* g      = (float*)alloc((size_t)N * 128 * 4);  // xp (N x 16) first, then S (fp32)
  float* zd     = (float*)alloc((size_t)N * 4);
  float* v      = (float*)alloc(128 * 4);
  float* c0     = (float*)alloc(4);
  float* xp     = g;                                   // alias: dead before aggH writes g

  hipMemsetAsync(d_ws, 0, zspan, stream);
  deg_kernel<<<(E + 255) / 256, 256, 0, stream>>>(dst, cursor, E, nq, nr);
  dinv_bsum_pad_kernel<<<nb, 256, 0, stream>>>(cursor, dinv, bsum, x, xp, N, nq, nr);
  rowptr_vc0_kernel<<<nb, 256, 0, stream>>>(cursor, bsum, rows, cursor, N, E, nq, nr,
                                            W3, b3, lin_w, lin_b, v, c0);
  fill_part_kernel<<<nchunk * 8, 256, 0, stream>>>(src, dst, cursor, colsrc, E, nq, nr);
  agg9_gemm1_kernel<<<nb, 256, 0, stream>>>(xp, dinv, rows, colsrc, W1, b1, hA, N);
  aggH_kernel<<<(N + 3) / 4, 256, 0, stream>>>(hA, rows, colsrc, g, N);
  gemmz_kernel<<<(N + 127) / 128, 256, 0, stream>>>(g, W2, dinv, b2, v, zd, N);
  agg1_pool_kernel<<<nb, 256, 0, stream>>>(zd, dinv, rows, colsrc, batch, gsum, gcnt, N);
  final_kernel<<<1, 64, 0, stream>>>(gsum, gcnt, c0, out, G);
}